// Round 1
// baseline (2323.544 us; speedup 1.0000x reference)
//
#include <hip/hip_runtime.h>

typedef __bf16 bf16;
typedef __attribute__((ext_vector_type(4))) __bf16 bf16x4;
typedef __attribute__((ext_vector_type(8))) __bf16 bf16x8;
typedef __attribute__((ext_vector_type(4))) float f32x4;

#define B_ 8
#define T_ 12
#define N_ 2048
#define D_ 64

__device__ __forceinline__ void gload16(const void* g, void* l) {
  __builtin_amdgcn_global_load_lds((const __attribute__((address_space(1))) void*)g,
                                   (__attribute__((address_space(3))) void*)l, 16, 0, 0);
}

__device__ __forceinline__ float sigmoidf_(float x) {
  x = fminf(fmaxf(x, -30.f), 30.f);
  return 1.f / (1.f + __expf(-x));
}
__device__ __forceinline__ float tanhf_(float x) {
  x = fminf(fmaxf(x, -15.f), 15.f);
  float e = __expf(2.f * x);
  return (e - 1.f) / (e + 1.f);
}

struct EpiP {
  const bf16* aux0; const bf16* aux1;
  const float* bias; const float* hbuf; const float* rbuf;
  bf16* bo0; bf16* bo1;
  float* fo0; float* fo1;
  int i0, i1;
};

// C = P[M,K] @ Bt[NCOLS,K]^T  (both row-major, K-contiguous), NCOLS = 2048.
// BM=64, BN=128, BK=32. 256 threads = 4 waves (2x2), wave tile 32x64 (2x4 frags).
template<int EPI>
__global__ __launch_bounds__(256)
void gemm_bt(const bf16* __restrict__ P, long strideP,
             const bf16* __restrict__ Bt, long strideBt,
             int K, EpiP ep)
{
  __shared__ bf16 lsA[2][64 * 32];
  __shared__ bf16 lsB[2][128 * 32];
  const int tid = threadIdx.x;
  const int bz = blockIdx.z;
  const int m0 = blockIdx.y * 64;
  const int n0 = blockIdx.x * 128;
  const bf16* Pb = P + (long)bz * strideP;
  const bf16* Btb = Bt + (long)bz * strideBt;

  const int lane = tid & 63;
  const int wid = tid >> 6;
  const int wm = (wid >> 1) * 32, wn = (wid & 1) * 64;
  const int lr = lane & 15, lq = lane >> 4;

  f32x4 acc[2][4] = {};

  const int arow = tid >> 2;
  const int akc = (tid & 3) * 8;
  const long aoff = (long)(m0 + arow) * K + akc;
  const long boff0 = (long)(n0 + arow) * K + akc;
  const long boff1 = (long)(n0 + arow + 64) * K + akc;

  const int KT = K >> 5;
  // stage kt = 0
  gload16(Pb + aoff, &lsA[0][tid * 8]);
  gload16(Btb + boff0, &lsB[0][tid * 8]);
  gload16(Btb + boff1, &lsB[0][(tid + 256) * 8]);

  for (int kt = 0; kt < KT; ++kt) {
    __syncthreads();  // staging of kt complete (vmcnt drained), buf[kt^1] free
    if (kt + 1 < KT) {
      const int nb = (kt + 1) & 1;
      const long k = (long)(kt + 1) * 32;
      gload16(Pb + aoff + k, &lsA[nb][tid * 8]);
      gload16(Btb + boff0 + k, &lsB[nb][tid * 8]);
      gload16(Btb + boff1 + k, &lsB[nb][(tid + 256) * 8]);
    }
    const int cb = kt & 1;
    bf16x8 af[2], bfr[4];
#pragma unroll
    for (int mi = 0; mi < 2; ++mi)
      af[mi] = *(const bf16x8*)&lsA[cb][(wm + mi * 16 + lr) * 32 + lq * 8];
#pragma unroll
    for (int ni = 0; ni < 4; ++ni)
      bfr[ni] = *(const bf16x8*)&lsB[cb][(wn + ni * 16 + lr) * 32 + lq * 8];
#pragma unroll
    for (int mi = 0; mi < 2; ++mi)
#pragma unroll
      for (int ni = 0; ni < 4; ++ni)
        acc[mi][ni] = __builtin_amdgcn_mfma_f32_16x16x32_bf16(af[mi], bfr[ni], acc[mi][ni], 0, 0, 0);
  }

#pragma unroll
  for (int mi = 0; mi < 2; ++mi) {
#pragma unroll
    for (int ni = 0; ni < 4; ++ni) {
      f32x4 v = acc[mi][ni];
      const int col = n0 + wn + ni * 16 + lr;
#pragma unroll
      for (int j = 0; j < 4; ++j) {
        const int row = m0 + wm + mi * 16 + lq * 4 + j;
        const float val = v[j];
        if constexpr (EPI == 0) {
          // W-mult split store: rows < i0 -> bo0, else -> bo1 (per batch bz)
          if (row < ep.i0) ep.bo0[((long)(bz * ep.i0 + row) << 11) + col] = (bf16)val;
          else ep.bo1[((long)(bz * ep.i1 + (row - ep.i0)) << 11) + col] = (bf16)val;
        } else if constexpr (EPI == 1) {
          // m = bf16(u1 + 2*t); i0 = log2(Cg) (7 gate / 6 cand)
          const int bb = row >> ep.i0, c = row & ((1 << ep.i0) - 1);
          const int auxrow = (bb << (ep.i0 + 1)) + (1 << ep.i0) + c;
          const float u1 = (float)ep.aux0[((long)auxrow << 11) + col];
          ep.bo0[((long)row << 11) + col] = (bf16)(u1 + 2.f * val);
        } else if constexpr (EPI == 2) {
          // gate: zr = sigmoid(s + u0 - u2 + bias); z*h -> fo0(zh), r -> fo1
          const int bb = row >> 7, c = row & 127;
          const float u0 = (float)ep.aux0[((long)((bb << 8) + c) << 11) + col];
          const float u2 = (float)ep.aux1[((long)row << 11) + col];
          const float s = sigmoidf_(val + u0 - u2 + ep.bias[c]);
          if (c < 64) {
            const long q = ((long)((bb << 6) + c) << 11) + col;
            ep.fo0[q] = s * ep.hbuf[q];
          } else {
            ep.fo1[((long)((bb << 6) + (c - 64)) << 11) + col] = s;
          }
        } else {
          // cand: hc = tanh(s + v0 - v2 + bias); h = r*h + (1-r)*hc
          const int bb = row >> 6, c = row & 63;
          const float v0 = (float)ep.aux0[((long)((bb << 7) + c) << 11) + col];
          const float v2 = (float)ep.aux1[((long)row << 11) + col];
          const float hc = tanhf_(val + v0 - v2 + ep.bias[c]);
          const long q = ((long)row << 11) + col;
          const float rv = ep.rbuf[q];
          const float ho = ep.hbuf[q];
          ep.fo0[q] = rv * ho + (1.f - rv) * hc;
        }
      }
    }
  }
}

// inp16[(b*2048+n), 0:64] = bf16(x[b,t,n,:]); [64:128] = bf16(src_cm[(b*64+d), n]) transposed
__global__ __launch_bounds__(256)
void pack_inp(const float* __restrict__ x, int t,
              const float* __restrict__ src_cm,
              bf16* __restrict__ out)
{
  __shared__ float lds[64 * 129];  // [d][n], pitch 129
  const int b = blockIdx.y, n0 = blockIdx.x * 128, tid = threadIdx.x;
  const float* xt = x + ((long)(b * T_ + t) * N_) * D_;
#pragma unroll
  for (int i = 0; i < 8; ++i) {
    const int pos = tid + i * 256;        // 2048 float4: row = pos>>4, c4 = pos&15
    const int rown = pos >> 4, c4 = pos & 15;
    const float4 v = *(const float4*)&xt[((long)(n0 + rown) << 6) + c4 * 4];
    bf16x4 o = {(bf16)v.x, (bf16)v.y, (bf16)v.z, (bf16)v.w};
    *(bf16x4*)&out[((long)((b << 11) + n0 + rown) << 7) + c4 * 4] = o;
  }
#pragma unroll
  for (int i = 0; i < 8; ++i) {
    const int pos = tid + i * 256;        // 2048 float4: d = pos>>5, n4 = pos&31
    const int d = pos >> 5, n4 = pos & 31;
    const float4 v = *(const float4*)&src_cm[((long)((b << 6) + d) << 11) + n0 + n4 * 4];
    float* l = &lds[d * 129 + n4 * 4];
    l[0] = v.x; l[1] = v.y; l[2] = v.z; l[3] = v.w;
  }
  __syncthreads();
#pragma unroll
  for (int i = 0; i < 4; ++i) {
    const int pos = tid + i * 256;        // 1024: d8 = pos&7, rown = pos>>3
    const int d8 = pos & 7, rown = pos >> 3;
    bf16x8 o;
#pragma unroll
    for (int j = 0; j < 8; ++j) o[j] = (bf16)lds[(d8 * 8 + j) * 129 + rown];
    *(bf16x8*)&out[((long)((b << 11) + n0 + rown) << 7) + 64 + d8 * 8] = o;
  }
}

// out[b,t,n,d] = x[b,t,n,d] + h_cm[(b*64+d), n];  t==11: also last[b,n,d] = h
__global__ __launch_bounds__(256)
void out_add(const float* __restrict__ x, const float* __restrict__ h_cm,
             float* __restrict__ out, float* __restrict__ lastout, int t)
{
  __shared__ float lds[64 * 65];  // [d][n], pitch 65
  const int b = blockIdx.y, n0 = blockIdx.x * 64, tid = threadIdx.x;
#pragma unroll
  for (int i = 0; i < 4; ++i) {
    const int pos = tid + i * 256;        // 1024 float4: d = pos>>4, n4 = pos&15
    const int d = pos >> 4, n4 = pos & 15;
    const float4 v = *(const float4*)&h_cm[((long)((b << 6) + d) << 11) + n0 + n4 * 4];
    float* l = &lds[d * 65 + n4 * 4];
    l[0] = v.x; l[1] = v.y; l[2] = v.z; l[3] = v.w;
  }
  __syncthreads();
  const float* xt = x + ((long)(b * T_ + t) * N_) * D_;
  float* ot = out + ((long)(b * T_ + t) * N_) * D_;
#pragma unroll
  for (int i = 0; i < 4; ++i) {
    const int pos = tid + i * 256;        // 1024 float4: n = pos>>4, d4 = pos&15
    const int n = pos >> 4, d4 = pos & 15;
    const long base = ((long)(n0 + n) << 6) + d4 * 4;
    const float4 xv = *(const float4*)&xt[base];
    float4 hv;
    hv.x = lds[(d4 * 4 + 0) * 65 + n];
    hv.y = lds[(d4 * 4 + 1) * 65 + n];
    hv.z = lds[(d4 * 4 + 2) * 65 + n];
    hv.w = lds[(d4 * 4 + 3) * 65 + n];
    float4 o = {xv.x + hv.x, xv.y + hv.y, xv.z + hv.z, xv.w + hv.w};
    *(float4*)&ot[base] = o;
    if (t == T_ - 1) {
      *(float4*)&lastout[(((long)(b << 11) + n0 + n) << 6) + d4 * 4] = hv;
    }
  }
}

// h_cm[(b*64+d), n] = init_state[b, n, d]
__global__ __launch_bounds__(256)
void init_h(const float* __restrict__ s0, float* __restrict__ h_cm)
{
  __shared__ float lds[64 * 65];  // [n][d], pitch 65
  const int b = blockIdx.y, n0 = blockIdx.x * 64, tid = threadIdx.x;
#pragma unroll
  for (int i = 0; i < 4; ++i) {
    const int pos = tid + i * 256;        // n = pos>>4, d4 = pos&15
    const int n = pos >> 4, d4 = pos & 15;
    const float4 v = *(const float4*)&s0[(((long)(b << 11) + n0 + n) << 6) + d4 * 4];
    float* l = &lds[n * 65 + d4 * 4];
    l[0] = v.x; l[1] = v.y; l[2] = v.z; l[3] = v.w;
  }
  __syncthreads();
#pragma unroll
  for (int i = 0; i < 4; ++i) {
    const int pos = tid + i * 256;        // d = pos>>4, n4 = pos&15
    const int d = pos >> 4, n4 = pos & 15;
    float4 v;
    v.x = lds[(n4 * 4 + 0) * 65 + d];
    v.y = lds[(n4 * 4 + 1) * 65 + d];
    v.z = lds[(n4 * 4 + 2) * 65 + d];
    v.w = lds[(n4 * 4 + 3) * 65 + d];
    *(float4*)&h_cm[((long)((b << 6) + d) << 11) + n0 + n4 * 4] = v;
  }
}

__global__ __launch_bounds__(256)
void cvt_bf16(const float* __restrict__ in, bf16* __restrict__ out, long n4)
{
  long i = (long)blockIdx.x * 256 + threadIdx.x;
  const long step = (long)gridDim.x * 256;
  for (; i < n4; i += step) {
    const float4 v = ((const float4*)in)[i];
    bf16x4 o = {(bf16)v.x, (bf16)v.y, (bf16)v.z, (bf16)v.w};
    ((bf16x4*)out)[i] = o;
  }
}

// Wgt[(k*128+o)*128+c] = W_gate[k][c][o];  Wct[(k*64+o)*128+c] = W_cand[k][c][o]
__global__ __launch_bounds__(256)
void cvt_w(const float* __restrict__ Wg, const float* __restrict__ Wc,
           bf16* __restrict__ Wgt, bf16* __restrict__ Wct)
{
  const int tid0 = blockIdx.x * 256 + threadIdx.x;
  const int step = gridDim.x * 256;
  for (int i = tid0; i < 3 * 128 * 128; i += step) {
    const int k = i >> 14, o = (i >> 7) & 127, c = i & 127;
    Wgt[i] = (bf16)Wg[(k << 14) + (c << 7) + o];
  }
  for (int i = tid0; i < 3 * 64 * 128; i += step) {
    const int k = i >> 13, o = (i >> 7) & 63, c = i & 127;
    Wct[i] = (bf16)Wc[(k << 13) + (c << 6) + o];
  }
}

extern "C" void kernel_launch(void* const* d_in, const int* in_sizes, int n_in,
                              void* d_out, int out_size, void* d_ws, size_t ws_size,
                              hipStream_t stream) {
  (void)in_sizes; (void)n_in; (void)out_size; (void)ws_size;
  const float* x    = (const float*)d_in[0];
  const float* s0   = (const float*)d_in[1];
  const float* adj  = (const float*)d_in[2];
  const float* Wg   = (const float*)d_in[3];
  const float* bg   = (const float*)d_in[4];
  const float* Wc   = (const float*)d_in[5];
  const float* bc   = (const float*)d_in[6];
  float* out = (float*)d_out;
  float* lastout = out + (long)B_ * T_ * N_ * D_;

  char* wp = (char*)d_ws;
  auto alloc = [&](size_t bytes) { char* p = wp; wp += (bytes + 255) & ~(size_t)255; return p; };
  bf16*  A16   = (bf16*)alloc((size_t)N_ * N_ * 2);
  bf16*  Wgt   = (bf16*)alloc((size_t)384 * 128 * 2);
  bf16*  Wct   = (bf16*)alloc((size_t)192 * 128 * 2);
  float* h_cm  = (float*)alloc((size_t)512 * N_ * 4);
  bf16*  inp16 = (bf16*)alloc((size_t)B_ * N_ * 128 * 2);
  bf16*  U01   = (bf16*)alloc((size_t)2048 * N_ * 2);   // gate u0,u1 / cand v0,v1
  bf16*  U2    = (bf16*)alloc((size_t)1024 * N_ * 2);   // gate u2 / cand v2
  bf16*  m16   = (bf16*)alloc((size_t)1024 * N_ * 2);   // u1+2t / v1+2t
  float* zh    = (float*)alloc((size_t)512 * N_ * 4);   // z*h
  float* rbuf  = (float*)alloc((size_t)512 * N_ * 4);   // r

  cvt_bf16<<<2048, 256, 0, stream>>>(adj, A16, (long)N_ * N_ / 4);
  cvt_w<<<64, 256, 0, stream>>>(Wg, Wc, Wgt, Wct);
  init_h<<<dim3(32, 8), 256, 0, stream>>>(s0, h_cm);

  for (int t = 0; t < T_; ++t) {
    // --- gate ---
    pack_inp<<<dim3(16, 8), 256, 0, stream>>>(x, t, h_cm, inp16);
    { EpiP e{}; e.bo0 = U01; e.bo1 = U2; e.i0 = 256; e.i1 = 128;
      gemm_bt<0><<<dim3(16, 6, 8), 256, 0, stream>>>(Wgt, 0, inp16, (long)N_ * 128, 128, e); }
    { EpiP e{}; e.aux0 = U01; e.bo0 = m16; e.i0 = 7;
      gemm_bt<1><<<dim3(16, 16, 1), 256, 0, stream>>>(U2, 0, A16, 0, N_, e); }
    { EpiP e{}; e.aux0 = U01; e.aux1 = U2; e.bias = bg; e.hbuf = h_cm; e.fo0 = zh; e.fo1 = rbuf;
      gemm_bt<2><<<dim3(16, 16, 1), 256, 0, stream>>>(m16, 0, A16, 0, N_, e); }
    // --- candidate ---
    pack_inp<<<dim3(16, 8), 256, 0, stream>>>(x, t, zh, inp16);
    { EpiP e{}; e.bo0 = U01; e.bo1 = U2; e.i0 = 128; e.i1 = 64;
      gemm_bt<0><<<dim3(16, 3, 8), 256, 0, stream>>>(Wct, 0, inp16, (long)N_ * 128, 128, e); }
    { EpiP e{}; e.aux0 = U01; e.bo0 = m16; e.i0 = 6;
      gemm_bt<1><<<dim3(16, 8, 1), 256, 0, stream>>>(U2, 0, A16, 0, N_, e); }
    { EpiP e{}; e.aux0 = U01; e.aux1 = U2; e.bias = bc; e.hbuf = h_cm; e.rbuf = rbuf; e.fo0 = h_cm;
      gemm_bt<3><<<dim3(16, 8, 1), 256, 0, stream>>>(m16, 0, A16, 0, N_, e); }
    out_add<<<dim3(32, 8), 256, 0, stream>>>(x, h_cm, out, lastout, t);
  }
}

// Round 2
// 1284.956 us; speedup vs baseline: 1.8083x; 1.8083x over previous
//
#include <hip/hip_runtime.h>

typedef __bf16 bf16;
typedef __attribute__((ext_vector_type(4))) __bf16 bf16x4;
typedef __attribute__((ext_vector_type(8))) __bf16 bf16x8;
typedef __attribute__((ext_vector_type(4))) float f32x4;

#define B_ 8
#define T_ 12
#define N_ 2048
#define D_ 64

__device__ __forceinline__ void gload16(const void* g, void* l) {
  __builtin_amdgcn_global_load_lds((const __attribute__((address_space(1))) void*)g,
                                   (__attribute__((address_space(3))) void*)l, 16, 0, 0);
}

__device__ __forceinline__ float sigmoidf_(float x) {
  x = fminf(fmaxf(x, -30.f), 30.f);
  return 1.f / (1.f + __expf(-x));
}
__device__ __forceinline__ float tanhf_(float x) {
  x = fminf(fmaxf(x, -15.f), 15.f);
  float e = __expf(2.f * x);
  return (e - 1.f) / (e + 1.f);
}

struct EpiP {
  bf16* bo0; bf16* bo1; bf16* bo2;
  int i0;
};

// C = P[M,K] @ Bt[NCOLS,K]^T (both row-major, K-contiguous).
// BM=64, BN=128, BK=32. 256 threads = 4 waves (2x2), wave tile 32x64 (2x4 frags).
// EPI 0: 3-way row split (W-mult, chunk = i0 rows per k-index, per-batch bz)
// EPI 4: bo0[row*2048+col] = bf16(2*val)   (A^2 precompute, N must be 2048)
template<int EPI>
__global__ __launch_bounds__(256)
void gemm_bt(const bf16* __restrict__ P, long strideP,
             const bf16* __restrict__ Bt, long strideBt,
             int K, EpiP ep)
{
  __shared__ bf16 lsA[2][64 * 32];
  __shared__ bf16 lsB[2][128 * 32];
  const int tid = threadIdx.x;
  const int bz = blockIdx.z;
  const int m0 = blockIdx.y * 64;
  const int n0 = blockIdx.x * 128;
  const bf16* Pb = P + (long)bz * strideP;
  const bf16* Btb = Bt + (long)bz * strideBt;

  const int lane = tid & 63;
  const int wid = tid >> 6;
  const int wm = (wid >> 1) * 32, wn = (wid & 1) * 64;
  const int lr = lane & 15, lq = lane >> 4;

  f32x4 acc[2][4] = {};

  const int arow = tid >> 2;
  const int akc = (tid & 3) * 8;
  const long aoff = (long)(m0 + arow) * K + akc;
  const long boff0 = (long)(n0 + arow) * K + akc;
  const long boff1 = (long)(n0 + arow + 64) * K + akc;

  const int KT = K >> 5;
  gload16(Pb + aoff, &lsA[0][tid * 8]);
  gload16(Btb + boff0, &lsB[0][tid * 8]);
  gload16(Btb + boff1, &lsB[0][(tid + 256) * 8]);

  for (int kt = 0; kt < KT; ++kt) {
    __syncthreads();
    if (kt + 1 < KT) {
      const int nb = (kt + 1) & 1;
      const long k = (long)(kt + 1) * 32;
      gload16(Pb + aoff + k, &lsA[nb][tid * 8]);
      gload16(Btb + boff0 + k, &lsB[nb][tid * 8]);
      gload16(Btb + boff1 + k, &lsB[nb][(tid + 256) * 8]);
    }
    const int cb = kt & 1;
    bf16x8 af[2], bfr[4];
#pragma unroll
    for (int mi = 0; mi < 2; ++mi)
      af[mi] = *(const bf16x8*)&lsA[cb][(wm + mi * 16 + lr) * 32 + lq * 8];
#pragma unroll
    for (int ni = 0; ni < 4; ++ni)
      bfr[ni] = *(const bf16x8*)&lsB[cb][(wn + ni * 16 + lr) * 32 + lq * 8];
#pragma unroll
    for (int mi = 0; mi < 2; ++mi)
#pragma unroll
      for (int ni = 0; ni < 4; ++ni)
        acc[mi][ni] = __builtin_amdgcn_mfma_f32_16x16x32_bf16(af[mi], bfr[ni], acc[mi][ni], 0, 0, 0);
  }

#pragma unroll
  for (int mi = 0; mi < 2; ++mi) {
#pragma unroll
    for (int ni = 0; ni < 4; ++ni) {
      f32x4 v = acc[mi][ni];
      const int col = n0 + wn + ni * 16 + lr;
#pragma unroll
      for (int j = 0; j < 4; ++j) {
        const int row = m0 + wm + mi * 16 + lq * 4 + j;
        const float val = v[j];
        if constexpr (EPI == 0) {
          const int C = ep.i0;
          bf16* dst; int rr;
          if (row < C)          { dst = ep.bo0; rr = row; }
          else if (row < 2 * C) { dst = ep.bo1; rr = row - C; }
          else                  { dst = ep.bo2; rr = row - 2 * C; }
          dst[((long)(bz * C + rr) << 11) + col] = (bf16)val;
        } else {
          ep.bo0[((long)row << 11) + col] = (bf16)(2.f * val);
        }
      }
    }
  }
}

// Split-K graph GEMM: C[m,n] = sum_j P[m,j]*B[n,j] over j in [0,4096),
// j<2048 -> (P0,B0), j>=2048 -> (P1,B1). blockIdx.z = split s in [0, 2*halfSplit).
// slab length KS = 2048/halfSplit. Row stride of all operands = 2048 (K-contig).
// Stores f32 partials: part[(s*Mrows + row)*2048 + col].
__global__ __launch_bounds__(256)
void gemm_graph(const bf16* __restrict__ P0, const bf16* __restrict__ P1,
                const bf16* __restrict__ B0, const bf16* __restrict__ B1,
                float* __restrict__ part, int Mrows, int KS, int halfSplit)
{
  __shared__ bf16 lsA[2][64 * 32];
  __shared__ bf16 lsB[2][128 * 32];
  const int tid = threadIdx.x;
  const int s = blockIdx.z;
  const bool hi = s >= halfSplit;
  const long j0 = (long)(hi ? s - halfSplit : s) * KS;
  const bf16* Pb = (hi ? P1 : P0) + j0;
  const bf16* Bb = (hi ? B1 : B0) + j0;
  const int m0 = blockIdx.y * 64;
  const int n0 = blockIdx.x * 128;

  const int lane = tid & 63;
  const int wid = tid >> 6;
  const int wm = (wid >> 1) * 32, wn = (wid & 1) * 64;
  const int lr = lane & 15, lq = lane >> 4;

  f32x4 acc[2][4] = {};

  const int arow = tid >> 2;
  const int akc = (tid & 3) * 8;
  const long aoff = ((long)(m0 + arow) << 11) + akc;
  const long boff0 = ((long)(n0 + arow) << 11) + akc;
  const long boff1 = ((long)(n0 + arow + 64) << 11) + akc;

  const int KT = KS >> 5;
  gload16(Pb + aoff, &lsA[0][tid * 8]);
  gload16(Bb + boff0, &lsB[0][tid * 8]);
  gload16(Bb + boff1, &lsB[0][(tid + 256) * 8]);

  for (int kt = 0; kt < KT; ++kt) {
    __syncthreads();
    if (kt + 1 < KT) {
      const int nb = (kt + 1) & 1;
      const long k = (long)(kt + 1) * 32;
      gload16(Pb + aoff + k, &lsA[nb][tid * 8]);
      gload16(Bb + boff0 + k, &lsB[nb][tid * 8]);
      gload16(Bb + boff1 + k, &lsB[nb][(tid + 256) * 8]);
    }
    const int cb = kt & 1;
    bf16x8 af[2], bfr[4];
#pragma unroll
    for (int mi = 0; mi < 2; ++mi)
      af[mi] = *(const bf16x8*)&lsA[cb][(wm + mi * 16 + lr) * 32 + lq * 8];
#pragma unroll
    for (int ni = 0; ni < 4; ++ni)
      bfr[ni] = *(const bf16x8*)&lsB[cb][(wn + ni * 16 + lr) * 32 + lq * 8];
#pragma unroll
    for (int mi = 0; mi < 2; ++mi)
#pragma unroll
      for (int ni = 0; ni < 4; ++ni)
        acc[mi][ni] = __builtin_amdgcn_mfma_f32_16x16x32_bf16(af[mi], bfr[ni], acc[mi][ni], 0, 0, 0);
  }

  float* pp = part + (long)s * Mrows * 2048;
#pragma unroll
  for (int mi = 0; mi < 2; ++mi) {
#pragma unroll
    for (int ni = 0; ni < 4; ++ni) {
      f32x4 v = acc[mi][ni];
      const int col = n0 + wn + ni * 16 + lr;
#pragma unroll
      for (int j = 0; j < 4; ++j) {
        const int row = m0 + wm + mi * 16 + lq * 4 + j;
        pp[((long)row << 11) + col] = v[j];
      }
    }
  }
}

// gate reduce: zr = sigmoid(sum4(part) + u0 - u2 + bias); z (c<64): zh -> inp16 h-half (bf16, transposed);
// r (c>=64) -> r_cm f32.
__global__ __launch_bounds__(256)
void gate_reduce(const float* __restrict__ part, const bf16* __restrict__ U0,
                 const bf16* __restrict__ U2, const float* __restrict__ bias,
                 const float* __restrict__ h_cm, float* __restrict__ r_cm,
                 bf16* __restrict__ inp16)
{
  __shared__ float lds[64][65];
  const int b = blockIdx.y, n0 = blockIdx.x * 64, tid = threadIdx.x;
#pragma unroll
  for (int i = 0; i < 8; ++i) {
    const int pos = tid + i * 256;           // 2048 = 128 c x 16 n4
    const int c = pos >> 4, n4 = pos & 15;
    const int row = (b << 7) + c;
    const long col = n0 + n4 * 4;
    float4 sum = {0.f, 0.f, 0.f, 0.f};
#pragma unroll
    for (int s = 0; s < 4; ++s) {
      const float4 p = *(const float4*)&part[((long)(s * 1024 + row) << 11) + col];
      sum.x += p.x; sum.y += p.y; sum.z += p.z; sum.w += p.w;
    }
    const bf16x4 u0v = *(const bf16x4*)&U0[((long)row << 11) + col];
    const bf16x4 u2v = *(const bf16x4*)&U2[((long)row << 11) + col];
    const float bb = bias[c];
    float4 zr;
    zr.x = sigmoidf_(sum.x + (float)u0v[0] - (float)u2v[0] + bb);
    zr.y = sigmoidf_(sum.y + (float)u0v[1] - (float)u2v[1] + bb);
    zr.z = sigmoidf_(sum.z + (float)u0v[2] - (float)u2v[2] + bb);
    zr.w = sigmoidf_(sum.w + (float)u0v[3] - (float)u2v[3] + bb);
    if (c < 64) {
      const long q = ((long)((b << 6) + c) << 11) + col;
      const float4 h4 = *(const float4*)&h_cm[q];
      lds[c][n4 * 4 + 0] = zr.x * h4.x;
      lds[c][n4 * 4 + 1] = zr.y * h4.y;
      lds[c][n4 * 4 + 2] = zr.z * h4.z;
      lds[c][n4 * 4 + 3] = zr.w * h4.w;
    } else {
      *(float4*)&r_cm[((long)((b << 6) + (c - 64)) << 11) + col] = zr;
    }
  }
  __syncthreads();
#pragma unroll
  for (int i = 0; i < 2; ++i) {
    const int q = tid + i * 256;             // 512 = 64 n x 8 d8
    const int n = q >> 3, d8 = q & 7;
    bf16x8 o;
#pragma unroll
    for (int j = 0; j < 8; ++j) o[j] = (bf16)lds[d8 * 8 + j][n];
    *(bf16x8*)&inp16[(((long)(b << 11) + n0 + n) << 7) + 64 + d8 * 8] = o;
  }
}

// cand reduce: hc = tanh(sum8(part) + v0 - v2 + bias); h = r*h + (1-r)*hc
// -> h_cm f32 (in place) and inp16 h-half bf16 (transposed, for next step's gate).
__global__ __launch_bounds__(256)
void cand_reduce(const float* __restrict__ part, const bf16* __restrict__ V0,
                 const bf16* __restrict__ V2, const float* __restrict__ bias,
                 const float* __restrict__ r_cm, float* __restrict__ h_cm,
                 bf16* __restrict__ inp16)
{
  __shared__ float lds[64][65];
  const int b = blockIdx.y, n0 = blockIdx.x * 64, tid = threadIdx.x;
#pragma unroll
  for (int i = 0; i < 4; ++i) {
    const int pos = tid + i * 256;           // 1024 = 64 c x 16 n4
    const int c = pos >> 4, n4 = pos & 15;
    const int row = (b << 6) + c;
    const long col = n0 + n4 * 4;
    float4 sum = {0.f, 0.f, 0.f, 0.f};
#pragma unroll
    for (int s = 0; s < 8; ++s) {
      const float4 p = *(const float4*)&part[((long)(s * 512 + row) << 11) + col];
      sum.x += p.x; sum.y += p.y; sum.z += p.z; sum.w += p.w;
    }
    const bf16x4 v0v = *(const bf16x4*)&V0[((long)row << 11) + col];
    const bf16x4 v2v = *(const bf16x4*)&V2[((long)row << 11) + col];
    const float bb = bias[c];
    float4 hc;
    hc.x = tanhf_(sum.x + (float)v0v[0] - (float)v2v[0] + bb);
    hc.y = tanhf_(sum.y + (float)v0v[1] - (float)v2v[1] + bb);
    hc.z = tanhf_(sum.z + (float)v0v[2] - (float)v2v[2] + bb);
    hc.w = tanhf_(sum.w + (float)v0v[3] - (float)v2v[3] + bb);
    const long q = ((long)row << 11) + col;
    const float4 r4 = *(const float4*)&r_cm[q];
    const float4 h4 = *(const float4*)&h_cm[q];
    float4 hn;
    hn.x = r4.x * h4.x + (1.f - r4.x) * hc.x;
    hn.y = r4.y * h4.y + (1.f - r4.y) * hc.y;
    hn.z = r4.z * h4.z + (1.f - r4.z) * hc.z;
    hn.w = r4.w * h4.w + (1.f - r4.w) * hc.w;
    *(float4*)&h_cm[q] = hn;
    lds[c][n4 * 4 + 0] = hn.x;
    lds[c][n4 * 4 + 1] = hn.y;
    lds[c][n4 * 4 + 2] = hn.z;
    lds[c][n4 * 4 + 3] = hn.w;
  }
  __syncthreads();
#pragma unroll
  for (int i = 0; i < 2; ++i) {
    const int q = tid + i * 256;             // 512 = 64 n x 8 d8
    const int n = q >> 3, d8 = q & 7;
    bf16x8 o;
#pragma unroll
    for (int j = 0; j < 8; ++j) o[j] = (bf16)lds[d8 * 8 + j][n];
    *(bf16x8*)&inp16[(((long)(b << 11) + n0 + n) << 7) + 64 + d8 * 8] = o;
  }
}

// inp16[(b*2048+n), 0:64] = bf16(x[b,t,n,:])
__global__ __launch_bounds__(256)
void pack_x(const float* __restrict__ x, int t, bf16* __restrict__ inp16)
{
  const int i = blockIdx.x * 256 + threadIdx.x;   // 262144 = 8 b x 2048 n x 16 d4
  const int b = i >> 15, rem = i & 32767;
  const int n = rem >> 4, d4 = rem & 15;
  const float4 v = *(const float4*)&x[(((long)(b * T_ + t) * N_ + n) << 6) + d4 * 4];
  bf16x4 o = {(bf16)v.x, (bf16)v.y, (bf16)v.z, (bf16)v.w};
  *(bf16x4*)&inp16[(((long)(b << 11) + n) << 7) + d4 * 4] = o;
}

// out[b,t,n,d] = x[b,t,n,d] + h_cm[(b*64+d), n];  t==11: also last[b,n,d] = h
__global__ __launch_bounds__(256)
void out_add(const float* __restrict__ x, const float* __restrict__ h_cm,
             float* __restrict__ out, float* __restrict__ lastout, int t)
{
  __shared__ float lds[64 * 65];
  const int b = blockIdx.y, n0 = blockIdx.x * 64, tid = threadIdx.x;
#pragma unroll
  for (int i = 0; i < 4; ++i) {
    const int pos = tid + i * 256;
    const int d = pos >> 4, n4 = pos & 15;
    const float4 v = *(const float4*)&h_cm[((long)((b << 6) + d) << 11) + n0 + n4 * 4];
    float* l = &lds[d * 65 + n4 * 4];
    l[0] = v.x; l[1] = v.y; l[2] = v.z; l[3] = v.w;
  }
  __syncthreads();
  const float* xt = x + ((long)(b * T_ + t) * N_) * D_;
  float* ot = out + ((long)(b * T_ + t) * N_) * D_;
#pragma unroll
  for (int i = 0; i < 4; ++i) {
    const int pos = tid + i * 256;
    const int n = pos >> 4, d4 = pos & 15;
    const long base = ((long)(n0 + n) << 6) + d4 * 4;
    const float4 xv = *(const float4*)&xt[base];
    float4 hv;
    hv.x = lds[(d4 * 4 + 0) * 65 + n];
    hv.y = lds[(d4 * 4 + 1) * 65 + n];
    hv.z = lds[(d4 * 4 + 2) * 65 + n];
    hv.w = lds[(d4 * 4 + 3) * 65 + n];
    float4 o = {xv.x + hv.x, xv.y + hv.y, xv.z + hv.z, xv.w + hv.w};
    *(float4*)&ot[base] = o;
    if (t == T_ - 1) {
      *(float4*)&lastout[(((long)(b << 11) + n0 + n) << 6) + d4 * 4] = hv;
    }
  }
}

// h_cm[(b*64+d), n] = init_state[b,n,d]; also inp16 h-half = bf16(init_state)
__global__ __launch_bounds__(256)
void init_h(const float* __restrict__ s0, float* __restrict__ h_cm,
            bf16* __restrict__ inp16)
{
  __shared__ float lds[64 * 65];
  const int b = blockIdx.y, n0 = blockIdx.x * 64, tid = threadIdx.x;
#pragma unroll
  for (int i = 0; i < 4; ++i) {
    const int pos = tid + i * 256;
    const int n = pos >> 4, d4 = pos & 15;
    const float4 v = *(const float4*)&s0[(((long)(b << 11) + n0 + n) << 6) + d4 * 4];
    float* l = &lds[n * 65 + d4 * 4];
    l[0] = v.x; l[1] = v.y; l[2] = v.z; l[3] = v.w;
    bf16x4 o = {(bf16)v.x, (bf16)v.y, (bf16)v.z, (bf16)v.w};
    *(bf16x4*)&inp16[(((long)(b << 11) + n0 + n) << 7) + 64 + d4 * 4] = o;
  }
  __syncthreads();
#pragma unroll
  for (int i = 0; i < 4; ++i) {
    const int pos = tid + i * 256;
    const int d = pos >> 4, n4 = pos & 15;
    float4 v;
    v.x = lds[(n4 * 4 + 0) * 65 + d];
    v.y = lds[(n4 * 4 + 1) * 65 + d];
    v.z = lds[(n4 * 4 + 2) * 65 + d];
    v.w = lds[(n4 * 4 + 3) * 65 + d];
    *(float4*)&h_cm[((long)((b << 6) + d) << 11) + n0 + n4 * 4] = v;
  }
}

__global__ __launch_bounds__(256)
void cvt_bf16(const float* __restrict__ in, bf16* __restrict__ out, long n4)
{
  long i = (long)blockIdx.x * 256 + threadIdx.x;
  const long step = (long)gridDim.x * 256;
  for (; i < n4; i += step) {
    const float4 v = ((const float4*)in)[i];
    bf16x4 o = {(bf16)v.x, (bf16)v.y, (bf16)v.z, (bf16)v.w};
    ((bf16x4*)out)[i] = o;
  }
}

// 64x64-tile bf16 transpose: out[c,r] = in[r,c], 2048x2048
__global__ __launch_bounds__(256)
void transpose_bf(const bf16* __restrict__ in, bf16* __restrict__ out)
{
  __shared__ bf16 t[64][72];
  const int r0 = blockIdx.y * 64, c0 = blockIdx.x * 64, tid = threadIdx.x;
#pragma unroll
  for (int i = 0; i < 2; ++i) {
    const int pos = tid + i * 256;           // 512 = 64 r x 8 c8
    const int r = pos >> 3, c8 = pos & 7;
    const bf16x8 v = *(const bf16x8*)&in[((long)(r0 + r) << 11) + c0 + c8 * 8];
    *(bf16x8*)&t[r][c8 * 8] = v;
  }
  __syncthreads();
#pragma unroll
  for (int i = 0; i < 2; ++i) {
    const int pos = tid + i * 256;           // 512 = 64 c x 8 r8
    const int c = pos >> 3, r8 = pos & 7;
    bf16x8 o;
#pragma unroll
    for (int j = 0; j < 8; ++j) o[j] = t[r8 * 8 + j][c];
    *(bf16x8*)&out[((long)(c0 + c) << 11) + r0 + r8 * 8] = o;
  }
}

// Wgt[(k*128+o)*128+c] = W_gate[k][c][o];  Wct[(k*64+o)*128+c] = W_cand[k][c][o]
__global__ __launch_bounds__(256)
void cvt_w(const float* __restrict__ Wg, const float* __restrict__ Wc,
           bf16* __restrict__ Wgt, bf16* __restrict__ Wct)
{
  const int tid0 = blockIdx.x * 256 + threadIdx.x;
  const int step = gridDim.x * 256;
  for (int i = tid0; i < 3 * 128 * 128; i += step) {
    const int k = i >> 14, o = (i >> 7) & 127, c = i & 127;
    Wgt[i] = (bf16)Wg[(k << 14) + (c << 7) + o];
  }
  for (int i = tid0; i < 3 * 64 * 128; i += step) {
    const int k = i >> 13, o = (i >> 7) & 63, c = i & 127;
    Wct[i] = (bf16)Wc[(k << 13) + (c << 6) + o];
  }
}

extern "C" void kernel_launch(void* const* d_in, const int* in_sizes, int n_in,
                              void* d_out, int out_size, void* d_ws, size_t ws_size,
                              hipStream_t stream) {
  (void)in_sizes; (void)n_in; (void)out_size; (void)ws_size;
  const float* x    = (const float*)d_in[0];
  const float* s0   = (const float*)d_in[1];
  const float* adj  = (const float*)d_in[2];
  const float* Wg   = (const float*)d_in[3];
  const float* bg   = (const float*)d_in[4];
  const float* Wc   = (const float*)d_in[5];
  const float* bc   = (const float*)d_in[6];
  float* out = (float*)d_out;
  float* lastout = out + (long)B_ * T_ * N_ * D_;

  char* wp = (char*)d_ws;
  auto alloc = [&](size_t bytes) { char* p = wp; wp += (bytes + 255) & ~(size_t)255; return p; };
  bf16*  A16   = (bf16*)alloc((size_t)N_ * N_ * 2);          // 8 MB   adj (row-major)
  bf16*  At16  = (bf16*)alloc((size_t)N_ * N_ * 2);          // 8 MB   adj^T
  bf16*  G16   = (bf16*)alloc((size_t)N_ * N_ * 2);          // 8 MB   2*adj^2
  bf16*  Wgt   = (bf16*)alloc((size_t)384 * 128 * 2);
  bf16*  Wct   = (bf16*)alloc((size_t)192 * 128 * 2);
  float* h_cm  = (float*)alloc((size_t)512 * N_ * 4);        // 4 MB   h channel-major
  bf16*  inp16 = (bf16*)alloc((size_t)B_ * N_ * 128 * 2);    // 4 MB   [x_t | h/zh] node-major
  bf16*  U0    = (bf16*)alloc((size_t)1024 * N_ * 2);        // 4 MB
  bf16*  U1    = (bf16*)alloc((size_t)1024 * N_ * 2);        // 4 MB
  bf16*  U2    = (bf16*)alloc((size_t)1024 * N_ * 2);        // 4 MB
  float* part  = (float*)alloc((size_t)4 * 1024 * N_ * 4);   // 32 MB  split-K partials
  float* r_cm  = (float*)alloc((size_t)512 * N_ * 4);        // 4 MB

  // ---- precompute ----
  cvt_bf16<<<2048, 256, 0, stream>>>(adj, A16, (long)N_ * N_ / 4);
  transpose_bf<<<dim3(32, 32), 256, 0, stream>>>(A16, At16);
  cvt_w<<<64, 256, 0, stream>>>(Wg, Wc, Wgt, Wct);
  { EpiP e{}; e.bo0 = G16;   // G = 2*A@A : C[n,j] = sum_m A[n,m]*At[j,m]
    gemm_bt<4><<<dim3(16, 32, 1), 256, 0, stream>>>(A16, 0, At16, 0, N_, e); }
  init_h<<<dim3(32, 8), 256, 0, stream>>>(s0, h_cm, inp16);

  for (int t = 0; t < T_; ++t) {
    pack_x<<<1024, 256, 0, stream>>>(x, t, inp16);
    // gate: W-mult (u0,u1,u2), K=128 over inp16
    { EpiP e{}; e.bo0 = U0; e.bo1 = U1; e.bo2 = U2; e.i0 = 128;
      gemm_bt<0><<<dim3(16, 6, 8), 256, 0, stream>>>(Wgt, 0, inp16, (long)N_ * 128, 128, e); }
    // gate: graph GEMM u1@A^T + u2@(2A^2)^T, split-K=4
    gemm_graph<<<dim3(16, 16, 4), 256, 0, stream>>>(U1, U2, A16, G16, part, 1024, 1024, 2);
    gate_reduce<<<dim3(32, 8), 256, 0, stream>>>(part, U0, U2, bg, h_cm, r_cm, inp16);
    // cand: W-mult (v0,v1,v2) over [x_t | z*h]
    { EpiP e{}; e.bo0 = U0; e.bo1 = U1; e.bo2 = U2; e.i0 = 64;
      gemm_bt<0><<<dim3(16, 3, 8), 256, 0, stream>>>(Wct, 0, inp16, (long)N_ * 128, 128, e); }
    // cand: graph GEMM v1@A^T + v2@(2A^2)^T, split-K=8
    gemm_graph<<<dim3(16, 8, 8), 256, 0, stream>>>(U1, U2, A16, G16, part, 512, 512, 4);
    cand_reduce<<<dim3(32, 8), 256, 0, stream>>>(part, U0, U2, bc, r_cm, h_cm, inp16);
    out_add<<<dim3(32, 8), 256, 0, stream>>>(x, h_cm, out, lastout, t);
  }
}

// Round 3
// 1244.808 us; speedup vs baseline: 1.8666x; 1.0323x over previous
//
#include <hip/hip_runtime.h>

typedef __bf16 bf16;
typedef __attribute__((ext_vector_type(4))) __bf16 bf16x4;
typedef __attribute__((ext_vector_type(8))) __bf16 bf16x8;
typedef __attribute__((ext_vector_type(4))) float f32x4;

#define B_ 8
#define TT 12
#define N_ 2048
#define NROW 16384   // B_*N_

__device__ __forceinline__ void gload16(const void* g, void* l) {
  __builtin_amdgcn_global_load_lds((const __attribute__((address_space(1))) void*)g,
                                   (__attribute__((address_space(3))) void*)l, 16, 0, 0);
}

__device__ __forceinline__ float sigmoidf_(float x) {
  x = fminf(fmaxf(x, -30.f), 30.f);
  return 1.f / (1.f + __expf(-x));
}
__device__ __forceinline__ float tanhf_(float x) {
  x = fminf(fmaxf(x, -15.f), 15.f);
  float e = __expf(2.f * x);
  return (e - 1.f) / (e + 1.f);
}

struct WModes {
  bf16* cm[6]; int cmr[6];     // channel-major dst: cm[(cmr+rowl)*NROW + node]
  bf16* nm[6]; int nmc[6];     // node-major dst:    nm[node*nmpitch + nmc + rowl]
  int nmpitch;
};

// C[M,16384] = P[M,128] @ Bt^T. Bt row (node) composite: k<64 from bt0 (pitch 128),
// k>=64 from bt1 (pitch1, +boff1). BM=64, BN=128, BK=32, 4 waves (2x2), wave 32x64.
__global__ __launch_bounds__(256)
void wgemm(const bf16* __restrict__ P,
           const bf16* __restrict__ bt0, const bf16* __restrict__ bt1,
           int pitch1, int boff1, WModes md)
{
  __shared__ bf16 lsA[2][64 * 32];
  __shared__ bf16 lsB[2][128 * 32];
  __shared__ bf16 lsT[128][72];
  const int tid = threadIdx.x;
  const int m0 = blockIdx.y * 64;
  const int n0 = blockIdx.x * 128;
  const int lane = tid & 63, wid = tid >> 6;
  const int wm = (wid >> 1) * 32, wn = (wid & 1) * 64;
  const int lr = lane & 15, lq = lane >> 4;
  f32x4 acc[2][4] = {};

  const int ar = tid >> 2, akc = (tid & 3) * 8;

  for (int kt = 0; kt < 4; ++kt) {
    const int buf = kt & 1;
    // stage kt (single-buffer-ahead: stage then sync; K tiny so keep simple dbuf)
    if (kt == 0) {
      gload16(P + (long)(m0 + ar) * 128 + akc, &lsA[0][tid * 8]);
#pragma unroll
      for (int i = 0; i < 2; ++i) {
        const int idx = tid + i * 256;
        const int row = idx >> 2, kc = (idx & 3) * 8;
        const bf16* src = (kc < 64) ? bt0 + (long)(n0 + row) * 128 + kc
                                    : bt1 + (long)(n0 + row) * pitch1 + kc + boff1;
        gload16(src, &lsB[0][idx * 8]);
      }
    }
    __syncthreads();
    if (kt < 3) {
      const int nb = (kt + 1) & 1;
      const int k = (kt + 1) * 32 + akc;
      gload16(P + (long)(m0 + ar) * 128 + k, &lsA[nb][tid * 8]);
#pragma unroll
      for (int i = 0; i < 2; ++i) {
        const int idx = tid + i * 256;
        const int row = idx >> 2, kb = (kt + 1) * 32 + (idx & 3) * 8;
        const bf16* src = (kb < 64) ? bt0 + (long)(n0 + row) * 128 + kb
                                    : bt1 + (long)(n0 + row) * pitch1 + kb + boff1;
        gload16(src, &lsB[nb][idx * 8]);
      }
    }
    bf16x8 af[2], bfr[4];
#pragma unroll
    for (int mi = 0; mi < 2; ++mi)
      af[mi] = *(const bf16x8*)&lsA[buf][(wm + mi * 16 + lr) * 32 + lq * 8];
#pragma unroll
    for (int ni = 0; ni < 4; ++ni)
      bfr[ni] = *(const bf16x8*)&lsB[buf][(wn + ni * 16 + lr) * 32 + lq * 8];
#pragma unroll
    for (int mi = 0; mi < 2; ++mi)
#pragma unroll
      for (int ni = 0; ni < 4; ++ni)
        acc[mi][ni] = __builtin_amdgcn_mfma_f32_16x16x32_bf16(af[mi], bfr[ni], acc[mi][ni], 0, 0, 0);
    __syncthreads();
  }

  const int y = blockIdx.y;
  bf16* cm = md.cm[y];
  bf16* nm = md.nm[y];
  if (cm) {
    const int r0 = md.cmr[y];
#pragma unroll
    for (int mi = 0; mi < 2; ++mi)
#pragma unroll
      for (int ni = 0; ni < 4; ++ni) {
        f32x4 v = acc[mi][ni];
        const int col = n0 + wn + ni * 16 + lr;
#pragma unroll
        for (int j = 0; j < 4; ++j)
          cm[(long)(r0 + wm + mi * 16 + lq * 4 + j) * NROW + col] = (bf16)v[j];
      }
  }
  if (nm) {
#pragma unroll
    for (int mi = 0; mi < 2; ++mi)
#pragma unroll
      for (int ni = 0; ni < 4; ++ni) {
        f32x4 v = acc[mi][ni];
        const int cl = wn + ni * 16 + lr;       // node local
        const int rl = wm + mi * 16 + lq * 4;   // chan local base
        bf16x4 pk = {(bf16)v[0], (bf16)v[1], (bf16)v[2], (bf16)v[3]};
        *(bf16x4*)&lsT[cl][rl] = pk;
      }
    __syncthreads();
    const int c0 = md.nmc[y], pit = md.nmpitch;
#pragma unroll
    for (int i = 0; i < 4; ++i) {
      const int idx = tid + i * 256;            // 1024 = 128 node x 8 c8
      const int node = idx >> 3, c8 = idx & 7;
      bf16x8 o = *(bf16x8*)&lsT[node][c8 * 8];
      *(bf16x8*)&nm[(long)(n0 + node) * pit + c0 + c8 * 8] = o;
    }
  }
}

// Node-major graph GEMM: part[s][(b,n)][chan] = sum_k mat_s[n,k] * U_s[chan][(b,k)]
// s<2: mat=A16 (k slab s*1024), U=U1cm ; s>=2: mat=G16, U=U2cm.
// BM=128, BN=128/64, BK=32, 4 waves (2x2), wave 64 x BN/2.
template<int BN>
__global__ __launch_bounds__(256)
void graph_gemm(const bf16* __restrict__ A16, const bf16* __restrict__ G16,
                const bf16* __restrict__ U1, const bf16* __restrict__ U2,
                float* __restrict__ part)
{
  __shared__ bf16 lsA[2][128 * 32];
  __shared__ bf16 lsB[2][BN * 32];
  const int tid = threadIdx.x;
  const int m0 = blockIdx.x * 128;
  const int s = blockIdx.z;
  const int b = m0 >> 11;
  const int r0 = m0 & 2047;
  const bf16* mat = (s < 2 ? A16 : G16) + (long)r0 * 2048 + (s & 1) * 1024;
  const bf16* U = (s < 2 ? U1 : U2) + (long)b * 2048 + (s & 1) * 1024;

  const int lane = tid & 63, wid = tid >> 6;
  const int wm = (wid >> 1) * 64, wn = (wid & 1) * (BN / 2);
  const int lr = lane & 15, lq = lane >> 4;
  constexpr int NF = BN / 32;
  f32x4 acc[4][NF] = {};

  const int row2 = tid >> 2, kc2 = (tid & 3) * 8;
  // stage kt=0
#pragma unroll
  for (int i = 0; i < 2; ++i) {
    const int idx = tid + i * 256;
    gload16(mat + (long)(idx >> 2) * 2048 + (idx & 3) * 8, &lsA[0][idx * 8]);
  }
#pragma unroll
  for (int i = 0; i < (BN == 128 ? 2 : 1); ++i) {
    const int idx = tid + i * 256;
    gload16(U + (long)(idx >> 2) * NROW + (idx & 3) * 8, &lsB[0][idx * 8]);
  }

  for (int kt = 0; kt < 32; ++kt) {
    __syncthreads();
    if (kt < 31) {
      const int nb = (kt + 1) & 1;
      const int k = (kt + 1) * 32;
#pragma unroll
      for (int i = 0; i < 2; ++i) {
        const int idx = tid + i * 256;
        gload16(mat + (long)(idx >> 2) * 2048 + k + (idx & 3) * 8, &lsA[nb][idx * 8]);
      }
#pragma unroll
      for (int i = 0; i < (BN == 128 ? 2 : 1); ++i) {
        const int idx = tid + i * 256;
        gload16(U + (long)(idx >> 2) * NROW + k + (idx & 3) * 8, &lsB[nb][idx * 8]);
      }
    }
    const int cb = kt & 1;
    bf16x8 af[4], bfr[NF];
#pragma unroll
    for (int mi = 0; mi < 4; ++mi)
      af[mi] = *(const bf16x8*)&lsA[cb][(wm + mi * 16 + lr) * 32 + lq * 8];
#pragma unroll
    for (int ni = 0; ni < NF; ++ni)
      bfr[ni] = *(const bf16x8*)&lsB[cb][(wn + ni * 16 + lr) * 32 + lq * 8];
#pragma unroll
    for (int mi = 0; mi < 4; ++mi)
#pragma unroll
      for (int ni = 0; ni < NF; ++ni)
        acc[mi][ni] = __builtin_amdgcn_mfma_f32_16x16x32_bf16(af[mi], bfr[ni], acc[mi][ni], 0, 0, 0);
  }
  (void)row2; (void)kc2;
  float* pp = part + ((long)s * NROW + m0) * BN;
#pragma unroll
  for (int mi = 0; mi < 4; ++mi)
#pragma unroll
    for (int ni = 0; ni < NF; ++ni) {
      f32x4 v = acc[mi][ni];
      const int chan = wn + ni * 16 + lr;
#pragma unroll
      for (int j = 0; j < 4; ++j)
        pp[(long)(wm + mi * 16 + lq * 4 + j) * BN + chan] = v[j];
    }
}

// gate: zr = sigmoid(sum4 part + u0 - u2 + bias); c<64 -> zh16 = z*h ; c>=64 -> r16
__global__ __launch_bounds__(256)
void gate_reduce(const float* __restrict__ part, const bf16* __restrict__ U0nm,
                 const bf16* __restrict__ U2nm, const float* __restrict__ bias,
                 const float* __restrict__ h_nm,
                 bf16* __restrict__ zh16, bf16* __restrict__ r16)
{
  const int tid = threadIdx.x;
  const long row = blockIdx.x * 32 + (tid >> 3);
  const int c16 = (tid & 7) * 16;
  float sum[16];
#pragma unroll
  for (int i = 0; i < 16; ++i) sum[i] = 0.f;
#pragma unroll
  for (int s = 0; s < 4; ++s) {
    const float* p = part + ((long)s * NROW + row) * 128 + c16;
#pragma unroll
    for (int i = 0; i < 4; ++i) {
      const float4 v = *(const float4*)&p[i * 4];
      sum[i * 4 + 0] += v.x; sum[i * 4 + 1] += v.y;
      sum[i * 4 + 2] += v.z; sum[i * 4 + 3] += v.w;
    }
  }
  const bf16x8 u0a = *(const bf16x8*)&U0nm[row * 128 + c16];
  const bf16x8 u0b = *(const bf16x8*)&U0nm[row * 128 + c16 + 8];
  const bf16x8 u2a = *(const bf16x8*)&U2nm[row * 128 + c16];
  const bf16x8 u2b = *(const bf16x8*)&U2nm[row * 128 + c16 + 8];
  float zr[16];
#pragma unroll
  for (int i = 0; i < 16; ++i) {
    const float u0 = (i < 8) ? (float)u0a[i] : (float)u0b[i - 8];
    const float u2 = (i < 8) ? (float)u2a[i] : (float)u2b[i - 8];
    zr[i] = sigmoidf_(sum[i] + u0 - u2 + bias[c16 + i]);
  }
  if (c16 < 64) {
#pragma unroll
    for (int i = 0; i < 4; ++i) {
      const float4 h4 = *(const float4*)&h_nm[row * 64 + c16 + i * 4];
      bf16x4 o = {(bf16)(zr[i*4+0] * h4.x), (bf16)(zr[i*4+1] * h4.y),
                  (bf16)(zr[i*4+2] * h4.z), (bf16)(zr[i*4+3] * h4.w)};
      *(bf16x4*)&zh16[row * 64 + c16 + i * 4] = o;
    }
  } else {
    const int c = c16 - 64;
#pragma unroll
    for (int i = 0; i < 4; ++i) {
      bf16x4 o = {(bf16)zr[i*4+0], (bf16)zr[i*4+1], (bf16)zr[i*4+2], (bf16)zr[i*4+3]};
      *(bf16x4*)&r16[row * 64 + c + i * 4] = o;
    }
  }
}

// cand: hc = tanh(sum4 part + v0 - v2 + bias); h = r*h+(1-r)*hc -> h_nm, inpG[t+1] h-half,
// out = x + h, lastout at t==11.
__global__ __launch_bounds__(256)
void cand_reduce(const float* __restrict__ part, const bf16* __restrict__ V0nm,
                 const bf16* __restrict__ V2nm, const float* __restrict__ bias,
                 const bf16* __restrict__ r16, float* __restrict__ h_nm,
                 bf16* __restrict__ inpG_next, const float* __restrict__ x,
                 float* __restrict__ out, float* __restrict__ lastout, int t)
{
  const int tid = threadIdx.x;
  const long row = blockIdx.x * 64 + (tid >> 2);
  const int c16 = (tid & 3) * 16;
  float sum[16];
#pragma unroll
  for (int i = 0; i < 16; ++i) sum[i] = 0.f;
#pragma unroll
  for (int s = 0; s < 4; ++s) {
    const float* p = part + ((long)s * NROW + row) * 64 + c16;
#pragma unroll
    for (int i = 0; i < 4; ++i) {
      const float4 v = *(const float4*)&p[i * 4];
      sum[i * 4 + 0] += v.x; sum[i * 4 + 1] += v.y;
      sum[i * 4 + 2] += v.z; sum[i * 4 + 3] += v.w;
    }
  }
  const bf16x8 v0a = *(const bf16x8*)&V0nm[row * 64 + c16];
  const bf16x8 v0b = *(const bf16x8*)&V0nm[row * 64 + c16 + 8];
  const bf16x8 v2a = *(const bf16x8*)&V2nm[row * 64 + c16];
  const bf16x8 v2b = *(const bf16x8*)&V2nm[row * 64 + c16 + 8];
  const bf16x8 ra = *(const bf16x8*)&r16[row * 64 + c16];
  const bf16x8 rb = *(const bf16x8*)&r16[row * 64 + c16 + 8];
  const int b = (int)(row >> 11), n = (int)(row & 2047);
  const long xoff = ((long)(b * TT + t) * N_ + n) * 64 + c16;
  float hn[16];
#pragma unroll
  for (int i = 0; i < 16; ++i) {
    const float v0 = (i < 8) ? (float)v0a[i] : (float)v0b[i - 8];
    const float v2 = (i < 8) ? (float)v2a[i] : (float)v2b[i - 8];
    const float rv = (i < 8) ? (float)ra[i] : (float)rb[i - 8];
    const float hc = tanhf_(sum[i] + v0 - v2 + bias[c16 + i]);
    const float ho = h_nm[row * 64 + c16 + i];
    hn[i] = rv * ho + (1.f - rv) * hc;
  }
#pragma unroll
  for (int i = 0; i < 4; ++i) {
    float4 h4 = {hn[i*4+0], hn[i*4+1], hn[i*4+2], hn[i*4+3]};
    *(float4*)&h_nm[row * 64 + c16 + i * 4] = h4;
    const float4 xv = *(const float4*)&x[xoff + i * 4];
    float4 o = {xv.x + h4.x, xv.y + h4.y, xv.z + h4.z, xv.w + h4.w};
    *(float4*)&out[xoff + i * 4] = o;
    if (inpG_next) {
      bf16x4 hb = {(bf16)h4.x, (bf16)h4.y, (bf16)h4.z, (bf16)h4.w};
      *(bf16x4*)&inpG_next[row * 128 + 64 + c16 + i * 4] = hb;
    }
    if (t == TT - 1) {
      *(float4*)&lastout[row * 64 + c16 + i * 4] = h4;
    }
  }
}

// x-halves of inpG for all t
__global__ __launch_bounds__(256)
void pack_x_all(const float* __restrict__ x, bf16* __restrict__ inpG)
{
  const int idx = blockIdx.x * 256 + threadIdx.x;   // 12*16384*8
  const int t = idx >> 17, rem = idx & 131071;
  const int row = rem >> 3, c8 = rem & 7;
  const int b = row >> 11, n = row & 2047;
  const float* src = &x[((long)(b * TT + t) * N_ + n) * 64 + c8 * 8];
  const float4 v0 = *(const float4*)&src[0];
  const float4 v1 = *(const float4*)&src[4];
  bf16x8 o = {(bf16)v0.x, (bf16)v0.y, (bf16)v0.z, (bf16)v0.w,
              (bf16)v1.x, (bf16)v1.y, (bf16)v1.z, (bf16)v1.w};
  *(bf16x8*)&inpG[((long)t * NROW + row) * 128 + c8 * 8] = o;
}

// h_nm = s0 ; inpG[0] h-half = bf16(s0)
__global__ __launch_bounds__(256)
void init_h0(const float* __restrict__ s0, float* __restrict__ h_nm,
             bf16* __restrict__ inpG0)
{
  const int idx = blockIdx.x * 256 + threadIdx.x;   // 16384*16
  const long row = idx >> 4;
  const int c4 = (idx & 15) * 4;
  const float4 v = *(const float4*)&s0[row * 64 + c4];
  *(float4*)&h_nm[row * 64 + c4] = v;
  bf16x4 o = {(bf16)v.x, (bf16)v.y, (bf16)v.z, (bf16)v.w};
  *(bf16x4*)&inpG0[row * 128 + 64 + c4] = o;
}

__global__ __launch_bounds__(256)
void cvt_bf16(const float* __restrict__ in, bf16* __restrict__ out, long n4)
{
  long i = (long)blockIdx.x * 256 + threadIdx.x;
  const long step = (long)gridDim.x * 256;
  for (; i < n4; i += step) {
    const float4 v = ((const float4*)in)[i];
    bf16x4 o = {(bf16)v.x, (bf16)v.y, (bf16)v.z, (bf16)v.w};
    ((bf16x4*)out)[i] = o;
  }
}

__global__ __launch_bounds__(256)
void transpose_bf(const bf16* __restrict__ in, bf16* __restrict__ out)
{
  __shared__ bf16 t[64][72];
  const int r0 = blockIdx.y * 64, c0 = blockIdx.x * 64, tid = threadIdx.x;
#pragma unroll
  for (int i = 0; i < 2; ++i) {
    const int pos = tid + i * 256;
    const int r = pos >> 3, c8 = pos & 7;
    const bf16x8 v = *(const bf16x8*)&in[((long)(r0 + r) << 11) + c0 + c8 * 8];
    *(bf16x8*)&t[r][c8 * 8] = v;
  }
  __syncthreads();
#pragma unroll
  for (int i = 0; i < 2; ++i) {
    const int pos = tid + i * 256;
    const int c = pos >> 3, r8 = pos & 7;
    bf16x8 o;
#pragma unroll
    for (int j = 0; j < 8; ++j) o[j] = t[r8 * 8 + j][c];
    *(bf16x8*)&out[((long)(c0 + c) << 11) + r0 + r8 * 8] = o;
  }
}

// G16 = bf16(2 * A@A): C[n,j] = 2*sum_m A16[n,m]*At16[j,m]
__global__ __launch_bounds__(256)
void gemm_sq(const bf16* __restrict__ P, const bf16* __restrict__ Bt,
             bf16* __restrict__ Gout)
{
  __shared__ bf16 lsA[2][64 * 32];
  __shared__ bf16 lsB[2][128 * 32];
  const int tid = threadIdx.x;
  const int m0 = blockIdx.y * 64;
  const int n0 = blockIdx.x * 128;
  const int lane = tid & 63, wid = tid >> 6;
  const int wm = (wid >> 1) * 32, wn = (wid & 1) * 64;
  const int lr = lane & 15, lq = lane >> 4;
  f32x4 acc[2][4] = {};
  const int arow = tid >> 2, akc = (tid & 3) * 8;
  const long aoff = ((long)(m0 + arow) << 11) + akc;
  const long boff0 = ((long)(n0 + arow) << 11) + akc;
  const long boff1 = ((long)(n0 + arow + 64) << 11) + akc;
  gload16(P + aoff, &lsA[0][tid * 8]);
  gload16(Bt + boff0, &lsB[0][tid * 8]);
  gload16(Bt + boff1, &lsB[0][(tid + 256) * 8]);
  for (int kt = 0; kt < 64; ++kt) {
    __syncthreads();
    if (kt < 63) {
      const int nb = (kt + 1) & 1;
      const long k = (long)(kt + 1) * 32;
      gload16(P + aoff + k, &lsA[nb][tid * 8]);
      gload16(Bt + boff0 + k, &lsB[nb][tid * 8]);
      gload16(Bt + boff1 + k, &lsB[nb][(tid + 256) * 8]);
    }
    const int cb = kt & 1;
    bf16x8 af[2], bfr[4];
#pragma unroll
    for (int mi = 0; mi < 2; ++mi)
      af[mi] = *(const bf16x8*)&lsA[cb][(wm + mi * 16 + lr) * 32 + lq * 8];
#pragma unroll
    for (int ni = 0; ni < 4; ++ni)
      bfr[ni] = *(const bf16x8*)&lsB[cb][(wn + ni * 16 + lr) * 32 + lq * 8];
#pragma unroll
    for (int mi = 0; mi < 2; ++mi)
#pragma unroll
      for (int ni = 0; ni < 4; ++ni)
        acc[mi][ni] = __builtin_amdgcn_mfma_f32_16x16x32_bf16(af[mi], bfr[ni], acc[mi][ni], 0, 0, 0);
  }
#pragma unroll
  for (int mi = 0; mi < 2; ++mi)
#pragma unroll
    for (int ni = 0; ni < 4; ++ni) {
      f32x4 v = acc[mi][ni];
      const int col = n0 + wn + ni * 16 + lr;
#pragma unroll
      for (int j = 0; j < 4; ++j)
        Gout[((long)(m0 + wm + mi * 16 + lq * 4 + j) << 11) + col] = (bf16)(2.f * v[j]);
    }
}

// Wgt[(k*128+o)][c] = Wg[k][c][o];  Wct[(k*64+o)][c] = Wc[k][c][o]
__global__ __launch_bounds__(256)
void cvt_w(const float* __restrict__ Wg, const float* __restrict__ Wc,
           bf16* __restrict__ Wgt, bf16* __restrict__ Wct)
{
  const int tid0 = blockIdx.x * 256 + threadIdx.x;
  const int step = gridDim.x * 256;
  for (int i = tid0; i < 3 * 128 * 128; i += step) {
    const int k = i >> 14, o = (i >> 7) & 127, c = i & 127;
    Wgt[i] = (bf16)Wg[(k << 14) + (c << 7) + o];
  }
  for (int i = tid0; i < 3 * 64 * 128; i += step) {
    const int k = i >> 13, o = (i >> 7) & 63, c = i & 127;
    Wct[i] = (bf16)Wc[(k << 13) + (c << 6) + o];
  }
}

extern "C" void kernel_launch(void* const* d_in, const int* in_sizes, int n_in,
                              void* d_out, int out_size, void* d_ws, size_t ws_size,
                              hipStream_t stream) {
  (void)in_sizes; (void)n_in; (void)out_size; (void)ws_size;
  const float* x   = (const float*)d_in[0];
  const float* s0  = (const float*)d_in[1];
  const float* adj = (const float*)d_in[2];
  const float* Wg  = (const float*)d_in[3];
  const float* bg  = (const float*)d_in[4];
  const float* Wc  = (const float*)d_in[5];
  const float* bc  = (const float*)d_in[6];
  float* out = (float*)d_out;
  float* lastout = out + (long)B_ * TT * N_ * 64;

  char* wp = (char*)d_ws;
  auto alloc = [&](size_t bytes) { char* p = wp; wp += (bytes + 255) & ~(size_t)255; return p; };
  bf16*  A16  = (bf16*)alloc((size_t)N_ * N_ * 2);
  bf16*  At16 = (bf16*)alloc((size_t)N_ * N_ * 2);
  bf16*  G16  = (bf16*)alloc((size_t)N_ * N_ * 2);
  bf16*  Wgt  = (bf16*)alloc((size_t)384 * 128 * 2);
  bf16*  Wct  = (bf16*)alloc((size_t)192 * 128 * 2);
  bf16*  inpG = (bf16*)alloc((size_t)TT * NROW * 128 * 2);   // 48 MB
  bf16*  U0nm = (bf16*)alloc((size_t)NROW * 128 * 2);
  bf16*  U1cm = (bf16*)alloc((size_t)128 * NROW * 2);
  bf16*  U2cm = (bf16*)alloc((size_t)128 * NROW * 2);
  bf16*  U2nm = (bf16*)alloc((size_t)NROW * 128 * 2);
  bf16*  V0nm = (bf16*)alloc((size_t)NROW * 64 * 2);
  bf16*  V1cm = (bf16*)alloc((size_t)64 * NROW * 2);
  bf16*  V2cm = (bf16*)alloc((size_t)64 * NROW * 2);
  bf16*  V2nm = (bf16*)alloc((size_t)NROW * 64 * 2);
  bf16*  zh16 = (bf16*)alloc((size_t)NROW * 64 * 2);
  bf16*  r16  = (bf16*)alloc((size_t)NROW * 64 * 2);
  float* h_nm = (float*)alloc((size_t)NROW * 64 * 4);
  float* part = (float*)alloc((size_t)4 * NROW * 128 * 4);   // 32 MB

  cvt_bf16<<<2048, 256, 0, stream>>>(adj, A16, (long)N_ * N_ / 4);
  transpose_bf<<<dim3(32, 32), 256, 0, stream>>>(A16, At16);
  cvt_w<<<64, 256, 0, stream>>>(Wg, Wc, Wgt, Wct);
  gemm_sq<<<dim3(16, 32), 256, 0, stream>>>(A16, At16, G16);
  pack_x_all<<<6144, 256, 0, stream>>>(x, inpG);
  init_h0<<<1024, 256, 0, stream>>>(s0, h_nm, inpG);

  for (int t = 0; t < TT; ++t) {
    bf16* inpG_t = inpG + (size_t)t * NROW * 128;
    // gate W-mult: y: 0,1 -> u0 nm ; 2,3 -> u1 cm ; 4,5 -> u2 cm+nm
    WModes mg{};
    mg.cm[2] = U1cm; mg.cmr[2] = 0;  mg.cm[3] = U1cm; mg.cmr[3] = 64;
    mg.cm[4] = U2cm; mg.cmr[4] = 0;  mg.cm[5] = U2cm; mg.cmr[5] = 64;
    mg.nm[0] = U0nm; mg.nmc[0] = 0;  mg.nm[1] = U0nm; mg.nmc[1] = 64;
    mg.nm[4] = U2nm; mg.nmc[4] = 0;  mg.nm[5] = U2nm; mg.nmc[5] = 64;
    mg.nmpitch = 128;
    wgemm<<<dim3(128, 6), 256, 0, stream>>>(Wgt, inpG_t, inpG_t, 128, 0, mg);
    graph_gemm<128><<<dim3(128, 1, 4), 256, 0, stream>>>(A16, G16, U1cm, U2cm, part);
    gate_reduce<<<512, 256, 0, stream>>>(part, U0nm, U2nm, bg, h_nm, zh16, r16);
    // cand W-mult: y: 0 -> v0 nm ; 1 -> v1 cm ; 2 -> v2 cm+nm. h-half from zh16.
    WModes mc{};
    mc.cm[1] = V1cm; mc.cmr[1] = 0;
    mc.cm[2] = V2cm; mc.cmr[2] = 0;
    mc.nm[0] = V0nm; mc.nmc[0] = 0;
    mc.nm[2] = V2nm; mc.nmc[2] = 0;
    mc.nmpitch = 64;
    wgemm<<<dim3(128, 3), 256, 0, stream>>>(Wct, inpG_t, zh16, 64, -64, mc);
    graph_gemm<64><<<dim3(128, 1, 4), 256, 0, stream>>>(A16, G16, V1cm, V2cm, part);
    cand_reduce<<<256, 256, 0, stream>>>(part, V0nm, V2nm, bc, r16, h_nm,
                                         (t < TT - 1) ? inpG + (size_t)(t + 1) * NROW * 128 : nullptr,
                                         x, out, lastout, t);
  }
}